// Round 1
// baseline (3554.910 us; speedup 1.0000x reference)
//
#include <hip/hip_runtime.h>
#include <float.h>
#include <stdint.h>

#pragma clang fp contract(off)

#define BATCH   2
#define N_ANCH  49104
#define NCLS    20
#define MAXDET  300
#define CAP     8192
#define NMS_T   512
#define PER     (CAP / NMS_T)      /* 16 */
#define FB_PER  96                 /* ceil(N_ANCH/512) */
#define TSEL    0.51f
#define SCTHR   0.05f
#define NEGF    (-1e9f)
#define HIC     511.0f
#define STDF    0.2f
#define DEAD    (-FLT_MAX)

// ---- workspace layout (bytes); total ~9.6 MB ----
static constexpr size_t OFF_BOXES = 0;                                    // [B][N][4] f32
static constexpr size_t SZ_BOXES  = (size_t)BATCH * N_ANCH * 4 * 4;
static constexpr size_t OFF_CS    = OFF_BOXES + SZ_BOXES;                 // [B*C][CAP] f32
static constexpr size_t SZ_CS     = (size_t)BATCH * NCLS * CAP * 4;
static constexpr size_t OFF_CI    = OFF_CS + SZ_CS;                       // [B*C][CAP] i32
static constexpr size_t SZ_CI     = SZ_CS;
static constexpr size_t OFF_CB    = OFF_CI + SZ_CI;                       // [B*C][CAP][4] f32
static constexpr size_t SZ_CB     = (size_t)BATCH * NCLS * CAP * 16;
static constexpr size_t OFF_CNT   = OFF_CB + SZ_CB;                       // [B*C] i32
static constexpr size_t SZ_CNT    = (size_t)BATCH * NCLS * 4;
static constexpr size_t OFF_SS    = OFF_CNT + ((SZ_CNT + 15) & ~(size_t)15); // [B*C][300] f32
static constexpr size_t SZ_SS     = (size_t)BATCH * NCLS * MAXDET * 4;
static constexpr size_t OFF_SI    = OFF_SS + SZ_SS;                       // [B*C][300] i32

// Exact replica of reference IoU decision:
// iou = inter / (((a_b + area) - inter) + 1e-8); suppress iff iou > 0.5
__device__ __forceinline__ bool iou_gt(float b0, float b1, float b2, float b3,
                                       float ab, float4 e) {
#pragma clang fp contract(off)
  float xx1 = fmaxf(b0, e.x);
  float yy1 = fmaxf(b1, e.y);
  float xx2 = fminf(b2, e.z);
  float yy2 = fminf(b3, e.w);
  float iw = fmaxf(xx2 - xx1, 0.0f);
  float ih = fmaxf(yy2 - yy1, 0.0f);
  float inter = iw * ih;
  float area = (e.z - e.x) * (e.w - e.y);
  float den = ab + area;
  den = den - inter;
  den = den + 1e-8f;
  float iou = inter / den;          // IEEE f32 divide (no fast-math in harness flags)
  return iou > 0.5f;
}

// block argmax of (score desc, index asc) over 512 threads; result broadcast via LDS
__device__ __forceinline__ void block_argmax(float bs, int bn,
                                             float* red_s, int* red_n,
                                             float* g_s, int* g_n) {
  for (int off = 32; off > 0; off >>= 1) {
    float os = __shfl_down(bs, off);
    int   on = __shfl_down(bn, off);
    if (os > bs || (os == bs && on < bn)) { bs = os; bn = on; }
  }
  int tid = threadIdx.x;
  if ((tid & 63) == 0) { red_s[tid >> 6] = bs; red_n[tid >> 6] = bn; }
  __syncthreads();
  if (tid == 0) {
    float gs = red_s[0]; int gn = red_n[0];
    for (int wv = 1; wv < NMS_T / 64; ++wv) {
      float rs = red_s[wv]; int rn = red_n[wv];
      if (rs > gs || (rs == gs && rn < gn)) { gs = rs; gn = rn; }
    }
    *g_s = gs; *g_n = gn;
  }
  __syncthreads();
}

// K1: decode+clip boxes, gather per-(b,c) candidates with score > TSEL
__global__ __launch_bounds__(256) void dec_gather(
    const float* __restrict__ anchors, const float* __restrict__ deltas,
    const float* __restrict__ cls, float* __restrict__ boxes,
    float* __restrict__ cand_s, int* __restrict__ cand_i,
    float* __restrict__ cand_b, int* __restrict__ cnt) {
#pragma clang fp contract(off)
  int id = blockIdx.x * 256 + threadIdx.x;     // id = b*N + n
  if (id >= BATCH * N_ANCH) return;
  int b = id / N_ANCH;
  int n = id - b * N_ANCH;
  float4 a = ((const float4*)anchors)[id];
  float4 d = ((const float4*)deltas)[id];
  float w = a.z - a.x;
  float h = a.w - a.y;
  float t;
  t = d.x * STDF; float x1 = a.x + t * w;      // (d*0.2f)*w then add — matches np order
  t = d.y * STDF; float y1 = a.y + t * h;
  t = d.z * STDF; float x2 = a.z + t * w;
  t = d.w * STDF; float y2 = a.w + t * h;
  x1 = fminf(fmaxf(x1, 0.0f), HIC);
  y1 = fminf(fmaxf(y1, 0.0f), HIC);
  x2 = fminf(fmaxf(x2, 0.0f), HIC);
  y2 = fminf(fmaxf(y2, 0.0f), HIC);
  float4 bx; bx.x = x1; bx.y = y1; bx.z = x2; bx.w = y2;
  ((float4*)boxes)[id] = bx;

  const float* row = cls + (size_t)id * NCLS;
  for (int c = 0; c < NCLS; ++c) {
    float s = row[c];
    if (s > TSEL) {
      int bc = b * NCLS + c;
      int pos = atomicAdd(cnt + bc, 1);
      if (pos < CAP) {
        cand_s[(size_t)bc * CAP + pos] = s;
        cand_i[(size_t)bc * CAP + pos] = n;
        ((float4*)cand_b)[(size_t)bc * CAP + pos] = bx;
      }
    }
  }
}

// K2: per-(b,c) greedy NMS, 300 steps. Fast path on pruned candidates;
// exact full-N fallback if the subset exhausts or overflowed.
__global__ __launch_bounds__(NMS_T) void nms_kernel(
    const float* __restrict__ cls, const float* __restrict__ boxes,
    const float* __restrict__ cand_s, const int* __restrict__ cand_i,
    const float* __restrict__ cand_b, const int* __restrict__ cnt,
    float* __restrict__ sel_s, int* __restrict__ sel_i) {
#pragma clang fp contract(off)
  __shared__ float red_s[NMS_T / 64];
  __shared__ int   red_n[NMS_T / 64];
  __shared__ float g_s;
  __shared__ int   g_n;
  __shared__ float wb[4];

  const int bc  = blockIdx.x;
  const int b   = bc / NCLS;
  const int c   = bc - b * NCLS;
  const int tid = threadIdx.x;
  const int count = cnt[bc];
  float* ss = sel_s + (size_t)bc * MAXDET;
  int*   si = sel_i + (size_t)bc * MAXDET;
  bool fb = (count > CAP);          // capacity overflow -> subset invalid -> fallback

  if (!fb) {
    const float*  cs = cand_s + (size_t)bc * CAP;
    const int*    ci = cand_i + (size_t)bc * CAP;
    const float4* cb = (const float4*)cand_b + (size_t)bc * CAP;
    float s[PER]; int nn[PER];
#pragma unroll
    for (int j = 0; j < PER; ++j) {
      int g = j * NMS_T + tid;
      if (g < count) { s[j] = cs[g]; nn[j] = ci[g]; }
      else           { s[j] = DEAD;  nn[j] = 0x7FFFFFFF; }
    }
    int k = 0;
    for (; k < MAXDET; ++k) {
      float bs = DEAD; int bn = 0x7FFFFFFF; int bj = 0;
#pragma unroll
      for (int j = 0; j < PER; ++j) {
        if (s[j] > bs || (s[j] == bs && nn[j] < bn)) { bs = s[j]; bn = nn[j]; bj = j; }
      }
      const float ls = bs; const int ln = bn;   // pre-reduction local best (owner detect)
      block_argmax(bs, bn, red_s, red_n, &g_s, &g_n);
      const float gs = g_s; const int gn = g_n;
      if (gs == DEAD) break;                    // subset exhausted before 300 -> fallback
      if (tid == 0) { ss[k] = gs; si[k] = gn; }
      if (ls == gs && ln == gn) {               // unique owner (anchor idx unique per class)
        float4 e = cb[bj * NMS_T + tid];
        wb[0] = e.x; wb[1] = e.y; wb[2] = e.z; wb[3] = e.w;
        s[bj] = DEAD; nn[bj] = 0x7FFFFFFF;
      }
      __syncthreads();
      const float b0 = wb[0], b1 = wb[1], b2 = wb[2], b3 = wb[3];
      const float ab = (b2 - b0) * (b3 - b1);
#pragma unroll
      for (int j = 0; j < PER; ++j) {
        if (s[j] != DEAD) {
          float4 e = cb[j * NMS_T + tid];
          if (iou_gt(b0, b1, b2, b3, ab, e)) { s[j] = DEAD; nn[j] = 0x7FFFFFFF; }
        }
      }
      // next iteration's first barrier (inside block_argmax) orders wb/g_s reuse
    }
    if (k >= MAXDET) return;
    fb = true;
  }

  // ---- exact full-N fallback (normally never executes; pure correctness insurance)
  {
    const float*  crow = cls + ((size_t)b * N_ANCH) * NCLS + c;  // stride NCLS
    const float4* bxs  = (const float4*)boxes + (size_t)b * N_ANCH;
    const int base = tid * FB_PER;   // contiguous ownership; 512*96 >= N
    float sc[FB_PER];
#pragma unroll
    for (int m = 0; m < FB_PER; ++m) {
      int n = base + m;
      float v = DEAD;                            // out-of-range: can never win
      if (n < N_ANCH) {
        float r = crow[(size_t)n * NCLS];
        v = (r > SCTHR) ? r : NEGF;              // thresholded score, like reference
      }
      sc[m] = v;
    }
    __syncthreads();
    for (int k = 0; k < MAXDET; ++k) {
      float bs = DEAD; int bn = 0x7FFFFFFF;
#pragma unroll
      for (int m = 0; m < FB_PER; ++m) {         // ascending n + strict > = first max
        if (sc[m] > bs) { bs = sc[m]; bn = base + m; }
      }
      block_argmax(bs, bn, red_s, red_n, &g_s, &g_n);
      const float gs = g_s; const int gn = g_n;  // all-NEG case -> gn==0, gs==NEG (matches np.argmax)
      if (tid == 0) { ss[k] = gs; si[k] = gn; }
      float4 w4 = bxs[gn];                       // broadcast load
      float ab = (w4.z - w4.x) * (w4.w - w4.y);
#pragma unroll
      for (int m = 0; m < FB_PER; ++m) {
        if (sc[m] > NEGF) {                      // live (real score); self gets IoU-suppressed
          float4 e = bxs[base + m];
          if (iou_gt(w4.x, w4.y, w4.z, w4.w, ab, e)) sc[m] = NEGF;
        }
      }
    }
  }
}

// K3: stable global top-300 per batch via exact rank counting
// (per-class lists are strictly descending in key = (score, -flatpos))
__global__ __launch_bounds__(512) void topk_kernel(
    const float* __restrict__ sel_s, const int* __restrict__ sel_i,
    const float* __restrict__ boxes, float* __restrict__ out) {
#pragma clang fp contract(off)
  __shared__ unsigned long long keys[NCLS * MAXDET];   // 48 KB
  const int b = blockIdx.x;
  const int tid = threadIdx.x;
  const float* ssb = sel_s + (size_t)b * NCLS * MAXDET;
  const int*   sib = sel_i + (size_t)b * NCLS * MAXDET;
  for (int e = tid; e < NCLS * MAXDET; e += 512) {
    unsigned int u = __float_as_uint(ssb[e]);
    u = (u & 0x80000000u) ? ~u : (u | 0x80000000u);    // order-preserving for floats
    keys[e] = ((unsigned long long)u << 32) |
              (unsigned long long)(0xFFFFFFFFu - (unsigned)e);
  }
  __syncthreads();
  for (int e = tid; e < NCLS * MAXDET; e += 512) {
    unsigned long long ke = keys[e];
    int rank = 0;
    for (int c2 = 0; c2 < NCLS; ++c2) {
      const unsigned long long* kc = keys + c2 * MAXDET;
      int lo = 0, hi = MAXDET;                          // first idx with kc[idx] <= ke
      while (lo < hi) {
        int mid = (lo + hi) >> 1;
        if (kc[mid] > ke) lo = mid + 1; else hi = mid;
      }
      rank += lo;
    }
    if (rank < MAXDET) {
      float s = ssb[e];
      int   n = sib[e];
      int   cc = e / MAXDET;
      bool valid = (s > NEGF * 0.5f);                   // top_sc > -5e8
      float4 bx = ((const float4*)boxes)[(size_t)b * N_ANCH + n];
      float* ob = out + ((size_t)b * MAXDET + rank) * 4;
      ob[0] = valid ? bx.x : -1.0f;
      ob[1] = valid ? bx.y : -1.0f;
      ob[2] = valid ? bx.z : -1.0f;
      ob[3] = valid ? bx.w : -1.0f;
      out[(size_t)BATCH * MAXDET * 4 + (size_t)b * MAXDET + rank] = valid ? s : -1.0f;
      out[(size_t)BATCH * MAXDET * 5 + (size_t)b * MAXDET + rank] =
          valid ? (float)cc : -1.0f;                    // labels as float (d_out is float*)
    }
  }
}

extern "C" void kernel_launch(void* const* d_in, const int* in_sizes, int n_in,
                              void* d_out, int out_size, void* d_ws, size_t ws_size,
                              hipStream_t stream) {
  (void)in_sizes; (void)n_in; (void)out_size; (void)ws_size;
  const float* anchors = (const float*)d_in[1];
  const float* deltas  = (const float*)d_in[2];
  const float* cls     = (const float*)d_in[3];   // d_in[0] = image: only shape used (512x512)
  char* ws = (char*)d_ws;
  float* boxes  = (float*)(ws + OFF_BOXES);
  float* cand_s = (float*)(ws + OFF_CS);
  int*   cand_i = (int*)  (ws + OFF_CI);
  float* cand_b = (float*)(ws + OFF_CB);
  int*   cnt    = (int*)  (ws + OFF_CNT);
  float* sel_s  = (float*)(ws + OFF_SS);
  int*   sel_i  = (int*)  (ws + OFF_SI);

  hipMemsetAsync(cnt, 0, SZ_CNT, stream);   // ws is re-poisoned 0xAA each call

  dec_gather<<<(BATCH * N_ANCH + 255) / 256, 256, 0, stream>>>(
      anchors, deltas, cls, boxes, cand_s, cand_i, cand_b, cnt);
  nms_kernel<<<BATCH * NCLS, NMS_T, 0, stream>>>(
      cls, boxes, cand_s, cand_i, cand_b, cnt, sel_s, sel_i);
  topk_kernel<<<BATCH, 512, 0, stream>>>(sel_s, sel_i, boxes, (float*)d_out);
}

// Round 2
// 1151.582 us; speedup vs baseline: 3.0870x; 3.0870x over previous
//
#include <hip/hip_runtime.h>
#include <float.h>
#include <stdint.h>

#pragma clang fp contract(off)

#define BATCH   2
#define N_ANCH  49104
#define NCLS    20
#define MAXDET  300
#define CAP     4096
#define NMS_T   512
#define PER     (CAP / NMS_T)      /* 8 */
#define FB_PER  96                 /* ceil(N_ANCH/512) */
#define TSEL    0.555f
#define SCTHR   0.05f
#define NEGF    (-1e9f)
#define HIC     511.0f
#define STDF    0.2f
#define DEAD    (-FLT_MAX)

// ---- workspace layout (bytes) ----
static constexpr size_t OFF_BOXES = 0;                                    // [B][N][4] f32
static constexpr size_t SZ_BOXES  = (size_t)BATCH * N_ANCH * 4 * 4;
static constexpr size_t OFF_CS    = OFF_BOXES + SZ_BOXES;                 // [B*C][CAP] f32
static constexpr size_t SZ_CS     = (size_t)BATCH * NCLS * CAP * 4;
static constexpr size_t OFF_CI    = OFF_CS + SZ_CS;                       // [B*C][CAP] i32
static constexpr size_t SZ_CI     = SZ_CS;
static constexpr size_t OFF_CB    = OFF_CI + SZ_CI;                       // [B*C][CAP][4] f32
static constexpr size_t SZ_CB     = (size_t)BATCH * NCLS * CAP * 16;
static constexpr size_t OFF_CNT   = OFF_CB + SZ_CB;                       // [B*C] i32
static constexpr size_t SZ_CNT    = (size_t)BATCH * NCLS * 4;
static constexpr size_t OFF_SS    = OFF_CNT + ((SZ_CNT + 15) & ~(size_t)15); // [B*C][300] f32
static constexpr size_t SZ_SS     = (size_t)BATCH * NCLS * MAXDET * 4;
static constexpr size_t OFF_SI    = OFF_SS + SZ_SS;                       // [B*C][300] i32

// Exact replica of reference IoU decision:
// iou = inter / (((a_b + area) - inter) + 1e-8); suppress iff iou > 0.5
__device__ __forceinline__ bool iou_gt(float b0, float b1, float b2, float b3,
                                       float ab, float4 e) {
#pragma clang fp contract(off)
  float xx1 = fmaxf(b0, e.x);
  float yy1 = fmaxf(b1, e.y);
  float xx2 = fminf(b2, e.z);
  float yy2 = fminf(b3, e.w);
  float iw = fmaxf(xx2 - xx1, 0.0f);
  float ih = fmaxf(yy2 - yy1, 0.0f);
  float inter = iw * ih;
  float area = (e.z - e.x) * (e.w - e.y);
  float den = ab + area;
  den = den - inter;
  den = den + 1e-8f;
  float iou = inter / den;          // IEEE f32 divide
  return iou > 0.5f;
}

// block argmax of (score desc, index asc); result broadcast via LDS (fallback path)
__device__ __forceinline__ void block_argmax(float bs, int bn,
                                             float* red_s, int* red_n,
                                             float* g_s, int* g_n) {
  for (int off = 32; off > 0; off >>= 1) {
    float os = __shfl_down(bs, off);
    int   on = __shfl_down(bn, off);
    if (os > bs || (os == bs && on < bn)) { bs = os; bn = on; }
  }
  int tid = threadIdx.x;
  if ((tid & 63) == 0) { red_s[tid >> 6] = bs; red_n[tid >> 6] = bn; }
  __syncthreads();
  if (tid == 0) {
    float gs = red_s[0]; int gn = red_n[0];
    for (int wv = 1; wv < NMS_T / 64; ++wv) {
      float rs = red_s[wv]; int rn = red_n[wv];
      if (rs > gs || (rs == gs && rn < gn)) { gs = rs; gn = rn; }
    }
    *g_s = gs; *g_n = gn;
  }
  __syncthreads();
}

// K1: decode+clip boxes, gather per-(b,c) candidates with score > TSEL.
// Two-phase LDS aggregation: <=40 global atomics per block instead of ~770.
__global__ __launch_bounds__(256) void dec_gather(
    const float* __restrict__ anchors, const float* __restrict__ deltas,
    const float* __restrict__ cls, float* __restrict__ boxes,
    float* __restrict__ cand_s, int* __restrict__ cand_i,
    float* __restrict__ cand_b, int* __restrict__ cnt) {
#pragma clang fp contract(off)
  __shared__ int lcnt[BATCH * NCLS];
  __shared__ int lbase[BATCH * NCLS];
  const int tid = threadIdx.x;
  const int id = blockIdx.x * 256 + tid;       // id = b*N + n
  const bool live = id < BATCH * N_ANCH;

  int b = 0, n = 0;
  float4 bx = {0.0f, 0.0f, 0.0f, 0.0f};
  if (live) {
    b = id / N_ANCH;
    n = id - b * N_ANCH;
    float4 a = ((const float4*)anchors)[id];
    float4 d = ((const float4*)deltas)[id];
    float w = a.z - a.x;
    float h = a.w - a.y;
    float t;
    t = d.x * STDF; float x1 = a.x + t * w;    // (d*0.2f)*w then add — matches np order
    t = d.y * STDF; float y1 = a.y + t * h;
    t = d.z * STDF; float x2 = a.z + t * w;
    t = d.w * STDF; float y2 = a.w + t * h;
    bx.x = fminf(fmaxf(x1, 0.0f), HIC);
    bx.y = fminf(fmaxf(y1, 0.0f), HIC);
    bx.z = fminf(fmaxf(x2, 0.0f), HIC);
    bx.w = fminf(fmaxf(y2, 0.0f), HIC);
    ((float4*)boxes)[id] = bx;
  }

  if (tid < BATCH * NCLS) lcnt[tid] = 0;
  __syncthreads();

  const float* row = cls + (size_t)id * NCLS;
  if (live) {
    for (int c = 0; c < NCLS; ++c) {
      if (row[c] > TSEL) atomicAdd(&lcnt[b * NCLS + c], 1);
    }
  }
  __syncthreads();

  if (tid < BATCH * NCLS) {
    int v = lcnt[tid];
    if (v > 0) lbase[tid] = atomicAdd(cnt + tid, v);
    lcnt[tid] = 0;                              // reuse as phase-C cursor
  }
  __syncthreads();

  if (live) {
    for (int c = 0; c < NCLS; ++c) {
      float s = row[c];
      if (s > TSEL) {
        int bc = b * NCLS + c;
        int p = atomicAdd(&lcnt[bc], 1);
        int pos = lbase[bc] + p;
        if (pos < CAP) {
          cand_s[(size_t)bc * CAP + pos] = s;
          cand_i[(size_t)bc * CAP + pos] = n;
          ((float4*)cand_b)[(size_t)bc * CAP + pos] = bx;
        }
      }
    }
  }
}

// K2: per-(b,c) greedy NMS, 300 steps. Fast path: everything in registers,
// joint (score,idx,box) reduction, 2 barriers/step. Exact full-N fallback
// if the pruned subset exhausts or overflowed CAP.
__global__ __launch_bounds__(NMS_T) void nms_kernel(
    const float* __restrict__ cls, const float* __restrict__ boxes,
    const float* __restrict__ cand_s, const int* __restrict__ cand_i,
    const float* __restrict__ cand_b, const int* __restrict__ cnt,
    float* __restrict__ sel_s, int* __restrict__ sel_i) {
#pragma clang fp contract(off)
  __shared__ float  red_s[NMS_T / 64];
  __shared__ int    red_n[NMS_T / 64];
  __shared__ float4 red_b[NMS_T / 64];
  __shared__ float  g_s;
  __shared__ int    g_n;
  __shared__ float4 g_b;

  const int bc  = blockIdx.x;
  const int b   = bc / NCLS;
  const int c   = bc - b * NCLS;
  const int tid = threadIdx.x;
  const int count = cnt[bc];
  float* ss = sel_s + (size_t)bc * MAXDET;
  int*   si = sel_i + (size_t)bc * MAXDET;
  bool fb = (count > CAP);          // capacity overflow -> subset invalid -> fallback

  if (!fb) {
    const float*  cs = cand_s + (size_t)bc * CAP;
    const int*    ci = cand_i + (size_t)bc * CAP;
    const float4* cb = (const float4*)cand_b + (size_t)bc * CAP;
    float  s[PER]; int nn[PER]; float4 bb[PER];
#pragma unroll
    for (int j = 0; j < PER; ++j) {
      int g = j * NMS_T + tid;
      if (g < count) { s[j] = cs[g]; nn[j] = ci[g]; bb[j] = cb[g]; }
      else { s[j] = DEAD; nn[j] = 0x7FFFFFFF; bb[j] = {0, 0, 0, 0}; }
    }
    int k = 0;
    for (; k < MAXDET; ++k) {
      // local argmax (score desc, anchor idx asc), carrying the box
      float bs = DEAD; int bn = 0x7FFFFFFF; float4 bbx = {0, 0, 0, 0};
#pragma unroll
      for (int j = 0; j < PER; ++j) {
        bool better = (s[j] > bs) || (s[j] == bs && nn[j] < bn);
        if (better) { bs = s[j]; bn = nn[j]; bbx = bb[j]; }
      }
      // wave reduce, carrying the box
      for (int off = 32; off > 0; off >>= 1) {
        float os = __shfl_down(bs, off);
        int   on = __shfl_down(bn, off);
        float ox = __shfl_down(bbx.x, off);
        float oy = __shfl_down(bbx.y, off);
        float oz = __shfl_down(bbx.z, off);
        float ow = __shfl_down(bbx.w, off);
        if (os > bs || (os == bs && on < bn)) {
          bs = os; bn = on; bbx.x = ox; bbx.y = oy; bbx.z = oz; bbx.w = ow;
        }
      }
      if ((tid & 63) == 0) {
        red_s[tid >> 6] = bs; red_n[tid >> 6] = bn; red_b[tid >> 6] = bbx;
      }
      __syncthreads();
      if (tid == 0) {
        float gs = red_s[0]; int gn = red_n[0]; float4 gb = red_b[0];
        for (int wv = 1; wv < NMS_T / 64; ++wv) {
          float rs = red_s[wv]; int rn = red_n[wv];
          if (rs > gs || (rs == gs && rn < gn)) { gs = rs; gn = rn; gb = red_b[wv]; }
        }
        g_s = gs; g_n = gn; g_b = gb;
        ss[k] = gs; si[k] = gn;
      }
      __syncthreads();
      const float gs = g_s; const int gn = g_n; const float4 w4 = g_b;
      if (gs == DEAD) break;        // subset exhausted before 300 -> fallback
      const float ab = (w4.z - w4.x) * (w4.w - w4.y);
#pragma unroll
      for (int j = 0; j < PER; ++j) {
        if (s[j] != DEAD) {
          if (nn[j] == gn || iou_gt(w4.x, w4.y, w4.z, w4.w, ab, bb[j])) {
            s[j] = DEAD; nn[j] = 0x7FFFFFFF;
          }
        }
      }
      // next iteration's first barrier orders g_*/red_* reuse
    }
    if (k >= MAXDET) return;
    fb = true;
  }

  // ---- exact full-N fallback (correctness insurance; normally never runs)
  {
    const float*  crow = cls + ((size_t)b * N_ANCH) * NCLS + c;  // stride NCLS
    const float4* bxs  = (const float4*)boxes + (size_t)b * N_ANCH;
    const int base = tid * FB_PER;   // contiguous ownership; 512*96 >= N
    float sc[FB_PER];
#pragma unroll
    for (int m = 0; m < FB_PER; ++m) {
      int n = base + m;
      float v = DEAD;                            // out-of-range: can never win
      if (n < N_ANCH) {
        float r = crow[(size_t)n * NCLS];
        v = (r > SCTHR) ? r : NEGF;              // thresholded score, like reference
      }
      sc[m] = v;
    }
    __syncthreads();
    for (int k = 0; k < MAXDET; ++k) {
      float bs = DEAD; int bn = 0x7FFFFFFF;
#pragma unroll
      for (int m = 0; m < FB_PER; ++m) {         // ascending n + strict > = first max
        if (sc[m] > bs) { bs = sc[m]; bn = base + m; }
      }
      block_argmax(bs, bn, red_s, red_n, &g_s, &g_n);
      const float gs = g_s; const int gn = g_n;  // all-NEG case -> gn==0 (matches np.argmax)
      if (tid == 0) { ss[k] = gs; si[k] = gn; }
      float4 w4 = bxs[gn];                       // broadcast load
      float ab = (w4.z - w4.x) * (w4.w - w4.y);
#pragma unroll
      for (int m = 0; m < FB_PER; ++m) {
        if (sc[m] > NEGF) {                      // live; self gets idx/IoU-suppressed
          float4 e = bxs[base + m];
          if (iou_gt(w4.x, w4.y, w4.z, w4.w, ab, e)) sc[m] = NEGF;
        }
      }
    }
  }
}

// K3: stable global top-300 per batch via exact rank counting
// (per-class lists are strictly descending in key = (score, -flatpos))
__global__ __launch_bounds__(512) void topk_kernel(
    const float* __restrict__ sel_s, const int* __restrict__ sel_i,
    const float* __restrict__ boxes, float* __restrict__ out) {
#pragma clang fp contract(off)
  __shared__ unsigned long long keys[NCLS * MAXDET];   // 48 KB
  const int b = blockIdx.x;
  const int tid = threadIdx.x;
  const float* ssb = sel_s + (size_t)b * NCLS * MAXDET;
  const int*   sib = sel_i + (size_t)b * NCLS * MAXDET;
  for (int e = tid; e < NCLS * MAXDET; e += 512) {
    unsigned int u = __float_as_uint(ssb[e]);
    u = (u & 0x80000000u) ? ~u : (u | 0x80000000u);    // order-preserving for floats
    keys[e] = ((unsigned long long)u << 32) |
              (unsigned long long)(0xFFFFFFFFu - (unsigned)e);
  }
  __syncthreads();
  for (int e = tid; e < NCLS * MAXDET; e += 512) {
    unsigned long long ke = keys[e];
    int rank = 0;
    for (int c2 = 0; c2 < NCLS; ++c2) {
      const unsigned long long* kc = keys + c2 * MAXDET;
      int lo = 0, hi = MAXDET;                          // first idx with kc[idx] <= ke
      while (lo < hi) {
        int mid = (lo + hi) >> 1;
        if (kc[mid] > ke) lo = mid + 1; else hi = mid;
      }
      rank += lo;
    }
    if (rank < MAXDET) {
      float s = ssb[e];
      int   n = sib[e];
      int   cc = e / MAXDET;
      bool valid = (s > NEGF * 0.5f);                   // top_sc > -5e8
      float4 bx = ((const float4*)boxes)[(size_t)b * N_ANCH + n];
      float* ob = out + ((size_t)b * MAXDET + rank) * 4;
      ob[0] = valid ? bx.x : -1.0f;
      ob[1] = valid ? bx.y : -1.0f;
      ob[2] = valid ? bx.z : -1.0f;
      ob[3] = valid ? bx.w : -1.0f;
      out[(size_t)BATCH * MAXDET * 4 + (size_t)b * MAXDET + rank] = valid ? s : -1.0f;
      out[(size_t)BATCH * MAXDET * 5 + (size_t)b * MAXDET + rank] =
          valid ? (float)cc : -1.0f;                    // labels as float
    }
  }
}

extern "C" void kernel_launch(void* const* d_in, const int* in_sizes, int n_in,
                              void* d_out, int out_size, void* d_ws, size_t ws_size,
                              hipStream_t stream) {
  (void)in_sizes; (void)n_in; (void)out_size; (void)ws_size;
  const float* anchors = (const float*)d_in[1];
  const float* deltas  = (const float*)d_in[2];
  const float* cls     = (const float*)d_in[3];   // d_in[0] = image: only shape used
  char* ws = (char*)d_ws;
  float* boxes  = (float*)(ws + OFF_BOXES);
  float* cand_s = (float*)(ws + OFF_CS);
  int*   cand_i = (int*)  (ws + OFF_CI);
  float* cand_b = (float*)(ws + OFF_CB);
  int*   cnt    = (int*)  (ws + OFF_CNT);
  float* sel_s  = (float*)(ws + OFF_SS);
  int*   sel_i  = (int*)  (ws + OFF_SI);

  hipMemsetAsync(cnt, 0, SZ_CNT, stream);   // ws is re-poisoned 0xAA each call

  dec_gather<<<(BATCH * N_ANCH + 255) / 256, 256, 0, stream>>>(
      anchors, deltas, cls, boxes, cand_s, cand_i, cand_b, cnt);
  nms_kernel<<<BATCH * NCLS, NMS_T, 0, stream>>>(
      cls, boxes, cand_s, cand_i, cand_b, cnt, sel_s, sel_i);
  topk_kernel<<<BATCH, 512, 0, stream>>>(sel_s, sel_i, boxes, (float*)d_out);
}

// Round 3
// 472.055 us; speedup vs baseline: 7.5307x; 2.4395x over previous
//
#include <hip/hip_runtime.h>
#include <float.h>
#include <stdint.h>

#pragma clang fp contract(off)

#define BATCH   2
#define N_ANCH  49104
#define NCLS    20
#define MAXDET  300
#define CAP     4096
#define SORT_T  512
#define FB_PER  96                 /* ceil(N_ANCH/512) */
#define TSEL    0.555f
#define SCTHR   0.05f
#define NEGF    (-1e9f)
#define HIC     511.0f
#define STDF    0.2f
#define DEAD    (-FLT_MAX)

// ---- workspace layout (bytes) ----
static constexpr size_t OFF_BOXES = 0;                                    // [B][N][4] f32
static constexpr size_t SZ_BOXES  = (size_t)BATCH * N_ANCH * 4 * 4;
static constexpr size_t OFF_CS    = OFF_BOXES + SZ_BOXES;                 // [B*C][CAP] f32
static constexpr size_t SZ_CS     = (size_t)BATCH * NCLS * CAP * 4;
static constexpr size_t OFF_CI    = OFF_CS + SZ_CS;                       // [B*C][CAP] i32
static constexpr size_t SZ_CI     = SZ_CS;
static constexpr size_t OFF_CNT   = OFF_CI + SZ_CI;                       // [B*C] i32
static constexpr size_t SZ_CNT    = (size_t)BATCH * NCLS * 4;
static constexpr size_t OFF_SS    = OFF_CNT + ((SZ_CNT + 15) & ~(size_t)15); // [B*C][300] f32
static constexpr size_t SZ_SS     = (size_t)BATCH * NCLS * MAXDET * 4;
static constexpr size_t OFF_SI    = OFF_SS + SZ_SS;                       // [B*C][300] i32

// Exact replica of reference IoU decision:
// iou = inter / (((a_b + area) - inter) + 1e-8); suppress iff iou > 0.5
__device__ __forceinline__ bool iou_gt(float b0, float b1, float b2, float b3,
                                       float ab, float4 e) {
#pragma clang fp contract(off)
  float xx1 = fmaxf(b0, e.x);
  float yy1 = fmaxf(b1, e.y);
  float xx2 = fminf(b2, e.z);
  float yy2 = fminf(b3, e.w);
  float iw = fmaxf(xx2 - xx1, 0.0f);
  float ih = fmaxf(yy2 - yy1, 0.0f);
  float inter = iw * ih;
  float area = (e.z - e.x) * (e.w - e.y);
  float den = ab + area;
  den = den - inter;
  den = den + 1e-8f;
  float iou = inter / den;          // IEEE f32 divide
  return iou > 0.5f;
}

// Same, with candidate area precomputed (identical arithmetic, hoisted)
__device__ __forceinline__ bool iou_gt_pa(float b0, float b1, float b2, float b3,
                                          float ab, float4 e, float earea) {
#pragma clang fp contract(off)
  float xx1 = fmaxf(b0, e.x);
  float yy1 = fmaxf(b1, e.y);
  float xx2 = fminf(b2, e.z);
  float yy2 = fminf(b3, e.w);
  float iw = fmaxf(xx2 - xx1, 0.0f);
  float ih = fmaxf(yy2 - yy1, 0.0f);
  float inter = iw * ih;
  float den = ab + earea;
  den = den - inter;
  den = den + 1e-8f;
  float iou = inter / den;
  return iou > 0.5f;
}

// block argmax of (score desc, index asc); result broadcast via LDS (fallback path)
__device__ __forceinline__ void block_argmax(float bs, int bn,
                                             float* red_s, int* red_n,
                                             float* g_s, int* g_n) {
  for (int off = 32; off > 0; off >>= 1) {
    float os = __shfl_down(bs, off);
    int   on = __shfl_down(bn, off);
    if (os > bs || (os == bs && on < bn)) { bs = os; bn = on; }
  }
  int tid = threadIdx.x;
  if ((tid & 63) == 0) { red_s[tid >> 6] = bs; red_n[tid >> 6] = bn; }
  __syncthreads();
  if (tid == 0) {
    float gs = red_s[0]; int gn = red_n[0];
    for (int wv = 1; wv < SORT_T / 64; ++wv) {
      float rs = red_s[wv]; int rn = red_n[wv];
      if (rs > gs || (rs == gs && rn < gn)) { gs = rs; gn = rn; }
    }
    *g_s = gs; *g_n = gn;
  }
  __syncthreads();
}

// K1: decode+clip boxes, gather per-(b,c) candidates with score > TSEL.
// Two-phase LDS aggregation: <=40 global atomics per block.
__global__ __launch_bounds__(256) void dec_gather(
    const float* __restrict__ anchors, const float* __restrict__ deltas,
    const float* __restrict__ cls, float* __restrict__ boxes,
    float* __restrict__ cand_s, int* __restrict__ cand_i,
    int* __restrict__ cnt) {
#pragma clang fp contract(off)
  __shared__ int lcnt[BATCH * NCLS];
  __shared__ int lbase[BATCH * NCLS];
  const int tid = threadIdx.x;
  const int id = blockIdx.x * 256 + tid;       // id = b*N + n
  const bool live = id < BATCH * N_ANCH;

  int b = 0, n = 0;
  if (live) {
    b = id / N_ANCH;
    n = id - b * N_ANCH;
    float4 a = ((const float4*)anchors)[id];
    float4 d = ((const float4*)deltas)[id];
    float w = a.z - a.x;
    float h = a.w - a.y;
    float t;
    t = d.x * STDF; float x1 = a.x + t * w;    // (d*0.2f)*w then add — matches np order
    t = d.y * STDF; float y1 = a.y + t * h;
    t = d.z * STDF; float x2 = a.z + t * w;
    t = d.w * STDF; float y2 = a.w + t * h;
    float4 bx;
    bx.x = fminf(fmaxf(x1, 0.0f), HIC);
    bx.y = fminf(fmaxf(y1, 0.0f), HIC);
    bx.z = fminf(fmaxf(x2, 0.0f), HIC);
    bx.w = fminf(fmaxf(y2, 0.0f), HIC);
    ((float4*)boxes)[id] = bx;
  }

  if (tid < BATCH * NCLS) lcnt[tid] = 0;
  __syncthreads();

  const float* row = cls + (size_t)id * NCLS;
  if (live) {
    for (int c = 0; c < NCLS; ++c) {
      if (row[c] > TSEL) atomicAdd(&lcnt[b * NCLS + c], 1);
    }
  }
  __syncthreads();

  if (tid < BATCH * NCLS) {
    int v = lcnt[tid];
    if (v > 0) lbase[tid] = atomicAdd(cnt + tid, v);
    lcnt[tid] = 0;                              // reuse as phase-C cursor
  }
  __syncthreads();

  if (live) {
    for (int c = 0; c < NCLS; ++c) {
      float s = row[c];
      if (s > TSEL) {
        int bc = b * NCLS + c;
        int p = atomicAdd(&lcnt[bc], 1);
        int pos = lbase[bc] + p;
        if (pos < CAP) {
          cand_s[(size_t)bc * CAP + pos] = s;
          cand_i[(size_t)bc * CAP + pos] = n;
        }
      }
    }
  }
}

// K2: per-(b,c) NMS. Bitonic-sort all candidates by (score desc, idx asc),
// then single-wave sorted scan (equivalent to greedy argmax NMS).
// Exact full-N fallback if subset overflowed or yields <300 accepts.
__global__ __launch_bounds__(SORT_T) void nms_kernel(
    const float* __restrict__ cls, const float* __restrict__ boxes,
    const float* __restrict__ cand_s, const int* __restrict__ cand_i,
    const int* __restrict__ cnt,
    float* __restrict__ sel_s, int* __restrict__ sel_i) {
#pragma clang fp contract(off)
  __shared__ unsigned long long keys[CAP];       // 32 KB
  __shared__ float4 accb[MAXDET];                // accepted boxes
  __shared__ float  acca[MAXDET];                // accepted areas
  __shared__ int    need_fb;
  __shared__ float  red_s[SORT_T / 64];
  __shared__ int    red_n[SORT_T / 64];
  __shared__ float  g_s;
  __shared__ int    g_n;

  const int bc  = blockIdx.x;
  const int b   = bc / NCLS;
  const int c   = bc - b * NCLS;
  const int tid = threadIdx.x;
  const int count = cnt[bc];
  float* ss = sel_s + (size_t)bc * MAXDET;
  int*   si = sel_i + (size_t)bc * MAXDET;
  const float4* bxs = (const float4*)boxes + (size_t)b * N_ANCH;
  bool fb = (count > CAP);          // capacity overflow -> subset invalid -> fallback

  if (!fb) {
    const float* cs = cand_s + (size_t)bc * CAP;
    const int*   ci = cand_i + (size_t)bc * CAP;
    // build keys: (score_bits|msb)<<32 | ~idx  — descending sort == argmax order
    for (int g = tid; g < CAP; g += SORT_T) {
      unsigned long long k = 0ull;               // padding sinks to the end
      if (g < count) {
        unsigned int u = __float_as_uint(cs[g]) | 0x80000000u;  // scores > 0
        k = ((unsigned long long)u << 32) | (unsigned int)(~ci[g]);
      }
      keys[g] = k;
    }
    __syncthreads();
    // bitonic sort, descending
    for (int kk = 2; kk <= CAP; kk <<= 1) {
      for (int j = kk >> 1; j > 0; j >>= 1) {
#pragma unroll
        for (int p = 0; p < CAP / SORT_T; ++p) {
          int i = tid + p * SORT_T;
          int ixj = i ^ j;
          if (ixj > i) {
            unsigned long long a = keys[i], bk = keys[ixj];
            bool ddir = ((i & kk) == 0);
            if ((a < bk) == ddir) { keys[i] = bk; keys[ixj] = a; }
          }
        }
        __syncthreads();
      }
    }
    // single-wave sorted scan (wave 0 only; no barriers inside)
    if (tid < 64) {
      const int lane = tid;
      int A = 0;
      bool done = false;
      const int nchunk = (count + 63) >> 6;
      for (int ch = 0; ch < nchunk && !done; ++ch) {
        const int g = (ch << 6) + lane;
        const bool have = g < count;
        unsigned long long key = have ? keys[g] : 0ull;
        const int idx = (int)(~((unsigned int)key));
        const float scv = __uint_as_float(((unsigned int)(key >> 32)) & 0x7FFFFFFFu);
        float4 bx = {0.0f, 0.0f, 0.0f, 0.0f};
        if (have) bx = bxs[idx];
        const float carea = (bx.z - bx.x) * (bx.w - bx.y);
        // phase 1: test vs all previously accepted (LDS broadcast reads)
        bool alive = have;
        for (int a = 0; a < A; ++a) {
          float4 abx = accb[a];
          float  aar = acca[a];
          if (alive && iou_gt_pa(abx.x, abx.y, abx.z, abx.w, aar, bx, carea))
            alive = false;
        }
        // phase 2: wave-synchronous in-chunk resolution, one accept per iter
        unsigned long long pend = __ballot(alive);
        while (pend) {
          const int jj = __ffsll(pend) - 1;      // lowest lane = highest key
          pend &= pend - 1;
          const float jx = __shfl(bx.x, jj);
          const float jy = __shfl(bx.y, jj);
          const float jz = __shfl(bx.z, jj);
          const float jw = __shfl(bx.w, jj);
          if (lane == jj) {
            ss[A] = scv; si[A] = idx;
            accb[A] = bx; acca[A] = carea;
          }
          A++;
          if (A == MAXDET) { done = true; break; }
          if (pend) {
            const float jar = (jz - jx) * (jw - jy);   // == accepted carea bitwise
            bool mine = (pend >> lane) & 1;
            bool sup = mine && iou_gt_pa(jx, jy, jz, jw, jar, bx, carea);
            pend &= ~__ballot(sup);
          }
        }
      }
      if (lane == 0) need_fb = (A < MAXDET) ? 1 : 0;
    }
    __syncthreads();
    fb = (need_fb != 0);
  }

  if (!fb) return;

  // ---- exact full-N fallback (correctness insurance; normally never runs)
  {
    const float* crow = cls + ((size_t)b * N_ANCH) * NCLS + c;  // stride NCLS
    const int base = tid * FB_PER;   // contiguous ownership; 512*96 >= N
    float sc[FB_PER];
#pragma unroll
    for (int m = 0; m < FB_PER; ++m) {
      int n = base + m;
      float v = DEAD;                            // out-of-range: can never win
      if (n < N_ANCH) {
        float r = crow[(size_t)n * NCLS];
        v = (r > SCTHR) ? r : NEGF;              // thresholded score, like reference
      }
      sc[m] = v;
    }
    __syncthreads();
    for (int k = 0; k < MAXDET; ++k) {
      float bs = DEAD; int bn = 0x7FFFFFFF;
#pragma unroll
      for (int m = 0; m < FB_PER; ++m) {         // ascending n + strict > = first max
        if (sc[m] > bs) { bs = sc[m]; bn = base + m; }
      }
      block_argmax(bs, bn, red_s, red_n, &g_s, &g_n);
      const float gs = g_s; const int gn = g_n;  // all-NEG case -> gn==0 (matches np.argmax)
      if (tid == 0) { ss[k] = gs; si[k] = gn; }
      float4 w4 = bxs[gn];                       // broadcast load
      float ab = (w4.z - w4.x) * (w4.w - w4.y);
#pragma unroll
      for (int m = 0; m < FB_PER; ++m) {
        if (sc[m] > NEGF) {                      // live; self gets IoU-suppressed
          float4 e = bxs[base + m];
          if (iou_gt(w4.x, w4.y, w4.z, w4.w, ab, e)) sc[m] = NEGF;
        }
      }
    }
  }
}

// K3: stable global top-300 per batch via exact rank counting
// (per-class lists are strictly descending in key = (score, -flatpos))
__global__ __launch_bounds__(512) void topk_kernel(
    const float* __restrict__ sel_s, const int* __restrict__ sel_i,
    const float* __restrict__ boxes, float* __restrict__ out) {
#pragma clang fp contract(off)
  __shared__ unsigned long long keys[NCLS * MAXDET];   // 48 KB
  const int b = blockIdx.x;
  const int tid = threadIdx.x;
  const float* ssb = sel_s + (size_t)b * NCLS * MAXDET;
  const int*   sib = sel_i + (size_t)b * NCLS * MAXDET;
  for (int e = tid; e < NCLS * MAXDET; e += 512) {
    unsigned int u = __float_as_uint(ssb[e]);
    u = (u & 0x80000000u) ? ~u : (u | 0x80000000u);    // order-preserving for floats
    keys[e] = ((unsigned long long)u << 32) |
              (unsigned long long)(0xFFFFFFFFu - (unsigned)e);
  }
  __syncthreads();
  for (int e = tid; e < NCLS * MAXDET; e += 512) {
    unsigned long long ke = keys[e];
    int rank = 0;
    for (int c2 = 0; c2 < NCLS; ++c2) {
      const unsigned long long* kc = keys + c2 * MAXDET;
      int lo = 0, hi = MAXDET;                          // first idx with kc[idx] <= ke
      while (lo < hi) {
        int mid = (lo + hi) >> 1;
        if (kc[mid] > ke) lo = mid + 1; else hi = mid;
      }
      rank += lo;
    }
    if (rank < MAXDET) {
      float s = ssb[e];
      int   n = sib[e];
      int   cc = e / MAXDET;
      bool valid = (s > NEGF * 0.5f);                   // top_sc > -5e8
      float4 bx = ((const float4*)boxes)[(size_t)b * N_ANCH + n];
      float* ob = out + ((size_t)b * MAXDET + rank) * 4;
      ob[0] = valid ? bx.x : -1.0f;
      ob[1] = valid ? bx.y : -1.0f;
      ob[2] = valid ? bx.z : -1.0f;
      ob[3] = valid ? bx.w : -1.0f;
      out[(size_t)BATCH * MAXDET * 4 + (size_t)b * MAXDET + rank] = valid ? s : -1.0f;
      out[(size_t)BATCH * MAXDET * 5 + (size_t)b * MAXDET + rank] =
          valid ? (float)cc : -1.0f;                    // labels as float
    }
  }
}

extern "C" void kernel_launch(void* const* d_in, const int* in_sizes, int n_in,
                              void* d_out, int out_size, void* d_ws, size_t ws_size,
                              hipStream_t stream) {
  (void)in_sizes; (void)n_in; (void)out_size; (void)ws_size;
  const float* anchors = (const float*)d_in[1];
  const float* deltas  = (const float*)d_in[2];
  const float* cls     = (const float*)d_in[3];   // d_in[0] = image: only shape used
  char* ws = (char*)d_ws;
  float* boxes  = (float*)(ws + OFF_BOXES);
  float* cand_s = (float*)(ws + OFF_CS);
  int*   cand_i = (int*)  (ws + OFF_CI);
  int*   cnt    = (int*)  (ws + OFF_CNT);
  float* sel_s  = (float*)(ws + OFF_SS);
  int*   sel_i  = (int*)  (ws + OFF_SI);

  hipMemsetAsync(cnt, 0, SZ_CNT, stream);   // ws is re-poisoned 0xAA each call

  dec_gather<<<(BATCH * N_ANCH + 255) / 256, 256, 0, stream>>>(
      anchors, deltas, cls, boxes, cand_s, cand_i, cnt);
  nms_kernel<<<BATCH * NCLS, SORT_T, 0, stream>>>(
      cls, boxes, cand_s, cand_i, cnt, sel_s, sel_i);
  topk_kernel<<<BATCH, 512, 0, stream>>>(sel_s, sel_i, boxes, (float*)d_out);
}

// Round 4
// 288.677 us; speedup vs baseline: 12.3145x; 1.6352x over previous
//
#include <hip/hip_runtime.h>
#include <float.h>
#include <stdint.h>

#pragma clang fp contract(off)

#define BATCH   2
#define N_ANCH  49104
#define NCLS    20
#define MAXDET  300
#define CAP     1024               /* pow2; expected candidates/class ~818 +- 28 */
#define KMAT    512                /* bit-matrix rows (sorted top-K) */
#define MATW    8                  /* KMAT/64 words per row */
#define NMS_T   512
#define FB_PER  96                 /* ceil(N_ANCH/512) */
#define TSEL    0.59f
#define SCTHR   0.05f
#define NEGF    (-1e9f)
#define HIC     511.0f
#define STDF    0.2f
#define DEAD    (-FLT_MAX)

typedef unsigned long long u64;

// ---- workspace layout (bytes) ----
static constexpr size_t OFF_BOXES = 0;                                    // [B][N][4] f32
static constexpr size_t SZ_BOXES  = (size_t)BATCH * N_ANCH * 4 * 4;
static constexpr size_t OFF_CS    = OFF_BOXES + SZ_BOXES;                 // [B*C][CAP] f32
static constexpr size_t SZ_CS     = (size_t)BATCH * NCLS * CAP * 4;
static constexpr size_t OFF_CI    = OFF_CS + SZ_CS;                       // [B*C][CAP] i32
static constexpr size_t SZ_CI     = SZ_CS;
static constexpr size_t OFF_CNT   = OFF_CI + SZ_CI;                       // [B*C] i32
static constexpr size_t SZ_CNT    = (size_t)BATCH * NCLS * 4;
static constexpr size_t OFF_SS    = OFF_CNT + ((SZ_CNT + 15) & ~(size_t)15); // [B*C][300] f32
static constexpr size_t SZ_SS     = (size_t)BATCH * NCLS * MAXDET * 4;
static constexpr size_t OFF_SI    = OFF_SS + SZ_SS;                       // [B*C][300] i32

// Exact replica of reference IoU decision:
// iou = inter / (((a_b + area) - inter) + 1e-8); suppress iff iou > 0.5
__device__ __forceinline__ bool iou_gt(float b0, float b1, float b2, float b3,
                                       float ab, float4 e) {
#pragma clang fp contract(off)
  float xx1 = fmaxf(b0, e.x);
  float yy1 = fmaxf(b1, e.y);
  float xx2 = fminf(b2, e.z);
  float yy2 = fminf(b3, e.w);
  float iw = fmaxf(xx2 - xx1, 0.0f);
  float ih = fmaxf(yy2 - yy1, 0.0f);
  float inter = iw * ih;
  float area = (e.z - e.x) * (e.w - e.y);
  float den = ab + area;
  den = den - inter;
  den = den + 1e-8f;
  float iou = inter / den;          // IEEE f32 divide
  return iou > 0.5f;
}

// Same with candidate area precomputed (identical arithmetic order)
__device__ __forceinline__ bool iou_gt_pa(float b0, float b1, float b2, float b3,
                                          float ab, float4 e, float earea) {
#pragma clang fp contract(off)
  float xx1 = fmaxf(b0, e.x);
  float yy1 = fmaxf(b1, e.y);
  float xx2 = fminf(b2, e.z);
  float yy2 = fminf(b3, e.w);
  float iw = fmaxf(xx2 - xx1, 0.0f);
  float ih = fmaxf(yy2 - yy1, 0.0f);
  float inter = iw * ih;
  float den = ab + earea;
  den = den - inter;
  den = den + 1e-8f;
  float iou = inter / den;
  return iou > 0.5f;
}

// block argmax (score desc, index asc); broadcast via LDS (full-N fallback path)
__device__ __forceinline__ void block_argmax(float bs, int bn,
                                             float* red_s, int* red_n,
                                             float* g_s, int* g_n) {
  for (int off = 32; off > 0; off >>= 1) {
    float os = __shfl_down(bs, off);
    int   on = __shfl_down(bn, off);
    if (os > bs || (os == bs && on < bn)) { bs = os; bn = on; }
  }
  int tid = threadIdx.x;
  if ((tid & 63) == 0) { red_s[tid >> 6] = bs; red_n[tid >> 6] = bn; }
  __syncthreads();
  if (tid == 0) {
    float gs = red_s[0]; int gn = red_n[0];
    for (int wv = 1; wv < NMS_T / 64; ++wv) {
      float rs = red_s[wv]; int rn = red_n[wv];
      if (rs > gs || (rs == gs && rn < gn)) { gs = rs; gn = rn; }
    }
    *g_s = gs; *g_n = gn;
  }
  __syncthreads();
}

// K1: decode+clip boxes, gather per-(b,c) candidates with score > TSEL.
__global__ __launch_bounds__(256) void dec_gather(
    const float* __restrict__ anchors, const float* __restrict__ deltas,
    const float* __restrict__ cls, float* __restrict__ boxes,
    float* __restrict__ cand_s, int* __restrict__ cand_i,
    int* __restrict__ cnt) {
#pragma clang fp contract(off)
  __shared__ int lcnt[BATCH * NCLS];
  __shared__ int lbase[BATCH * NCLS];
  const int tid = threadIdx.x;
  const int id = blockIdx.x * 256 + tid;       // id = b*N + n
  const bool live = id < BATCH * N_ANCH;

  int b = 0, n = 0;
  if (live) {
    b = id / N_ANCH;
    n = id - b * N_ANCH;
    float4 a = ((const float4*)anchors)[id];
    float4 d = ((const float4*)deltas)[id];
    float w = a.z - a.x;
    float h = a.w - a.y;
    float t;
    t = d.x * STDF; float x1 = a.x + t * w;    // (d*0.2f)*w then add — matches np order
    t = d.y * STDF; float y1 = a.y + t * h;
    t = d.z * STDF; float x2 = a.z + t * w;
    t = d.w * STDF; float y2 = a.w + t * h;
    float4 bx;
    bx.x = fminf(fmaxf(x1, 0.0f), HIC);
    bx.y = fminf(fmaxf(y1, 0.0f), HIC);
    bx.z = fminf(fmaxf(x2, 0.0f), HIC);
    bx.w = fminf(fmaxf(y2, 0.0f), HIC);
    ((float4*)boxes)[id] = bx;
  }

  if (tid < BATCH * NCLS) lcnt[tid] = 0;
  __syncthreads();

  const float* row = cls + (size_t)id * NCLS;
  if (live) {
    for (int c = 0; c < NCLS; ++c) {
      if (row[c] > TSEL) atomicAdd(&lcnt[b * NCLS + c], 1);
    }
  }
  __syncthreads();

  if (tid < BATCH * NCLS) {
    int v = lcnt[tid];
    if (v > 0) lbase[tid] = atomicAdd(cnt + tid, v);
    lcnt[tid] = 0;                              // reuse as phase-C cursor
  }
  __syncthreads();

  if (live) {
    for (int c = 0; c < NCLS; ++c) {
      float s = row[c];
      if (s > TSEL) {
        int bc = b * NCLS + c;
        int p = atomicAdd(&lcnt[bc], 1);
        int pos = lbase[bc] + p;
        if (pos < CAP) {
          cand_s[(size_t)bc * CAP + pos] = s;
          cand_i[(size_t)bc * CAP + pos] = n;
        }
      }
    }
  }
}

// K2: per-(b,c) NMS. Sort <=1024 candidates desc, build 512x512 IoU bit-matrix
// (block-parallel), then single-lane bit-walk (next accept == next clear bit).
// Ladder: matrix walk -> sorted single-wave scan -> exact full-N.
__global__ __launch_bounds__(NMS_T) void nms_kernel(
    const float* __restrict__ cls, const float* __restrict__ boxes,
    const float* __restrict__ cand_s, const int* __restrict__ cand_i,
    const int* __restrict__ cnt,
    float* __restrict__ sel_s, int* __restrict__ sel_i) {
#pragma clang fp contract(off)
  __shared__ u64    keys[CAP];                 // 8 KB
  __shared__ u64    mat[KMAT * MATW];          // 32 KB
  __shared__ float4 bxl[KMAT];                 // 8 KB
  __shared__ float4 accb[MAXDET];              // 4.8 KB (slow path)
  __shared__ float  acca[MAXDET];              // 1.2 KB
  __shared__ float  red_s[NMS_T / 64];
  __shared__ int    red_n[NMS_T / 64];
  __shared__ float  g_s;
  __shared__ int    g_n;
  __shared__ int    need_slow, need_fb;

  const int bc  = blockIdx.x;
  const int b   = bc / NCLS;
  const int c   = bc - b * NCLS;
  const int tid = threadIdx.x;
  const int count = cnt[bc];
  float* ss = sel_s + (size_t)bc * MAXDET;
  int*   si = sel_i + (size_t)bc * MAXDET;
  const float4* bxs = (const float4*)boxes + (size_t)b * N_ANCH;
  bool fullfb = (count > CAP);      // overflow -> subset invalid -> full-N

  if (!fullfb) {
    const float* cs = cand_s + (size_t)bc * CAP;
    const int*   ci = cand_i + (size_t)bc * CAP;
    // keys: (score_bits|msb)<<32 | ~idx — descending == greedy argmax order
    for (int g = tid; g < CAP; g += NMS_T) {
      u64 k = 0ull;                              // padding sinks to end
      if (g < count) {
        unsigned int u = __float_as_uint(cs[g]) | 0x80000000u;  // scores > 0
        k = ((u64)u << 32) | (unsigned int)(~ci[g]);
      }
      keys[g] = k;
    }
    __syncthreads();
    // bitonic sort (descending), 1024 keys, 512 threads
    for (int kk = 2; kk <= CAP; kk <<= 1) {
      for (int j = kk >> 1; j > 0; j >>= 1) {
#pragma unroll
        for (int p = 0; p < CAP / NMS_T; ++p) {
          int i = tid + p * NMS_T;
          int ixj = i ^ j;
          if (ixj > i) {
            u64 a = keys[i], bk = keys[ixj];
            bool ddir = ((i & kk) == 0);
            if ((a < bk) == ddir) { keys[i] = bk; keys[ixj] = a; }
          }
        }
        __syncthreads();
      }
    }
    const int K = (count < KMAT) ? count : KMAT;
    // stage top-K boxes (gather from L2 by sorted anchor idx)
    for (int g = tid; g < K; g += NMS_T) {
      int idx = (int)(~((unsigned int)keys[g]));
      bxl[g] = bxs[idx];
    }
    __syncthreads();
    // build symmetric IoU bit-matrix: task = (row-quad, word)
    for (int t = tid; t < (KMAT / 4) * MATW; t += NMS_T) {
      const int rq = t >> 3;                    // MATW == 8
      const int w  = t & 7;
      const int i0 = rq * 4;
      const int jbase = w * 64;
      u64 w0 = 0, w1 = 0, w2 = 0, w3 = 0;
      if (i0 < K && jbase < K && jbase + 64 > i0) {
        const int iA = i0, iB = min(i0 + 1, K - 1),
                  iC = min(i0 + 2, K - 1), iD = min(i0 + 3, K - 1);
        float4 rA = bxl[iA], rB = bxl[iB], rC = bxl[iC], rD = bxl[iD];
        float aA = (rA.z - rA.x) * (rA.w - rA.y);
        float aB = (rB.z - rB.x) * (rB.w - rB.y);
        float aC = (rC.z - rC.x) * (rC.w - rC.y);
        float aD = (rD.z - rD.x) * (rD.w - rD.y);
        const int jmax = min(64, K - jbase);
        for (int jj = 0; jj < jmax; ++jj) {
          float4 e = bxl[jbase + jj];
          float ea = (e.z - e.x) * (e.w - e.y);
          // self/sub-diagonal bits harmless (symmetric; earlier bits already set)
          w0 |= (u64)iou_gt_pa(rA.x, rA.y, rA.z, rA.w, aA, e, ea) << jj;
          w1 |= (u64)iou_gt_pa(rB.x, rB.y, rB.z, rB.w, aB, e, ea) << jj;
          w2 |= (u64)iou_gt_pa(rC.x, rC.y, rC.z, rC.w, aC, e, ea) << jj;
          w3 |= (u64)iou_gt_pa(rD.x, rD.y, rD.z, rD.w, aD, e, ea) << jj;
        }
      }
      mat[(i0 + 0) * MATW + w] = w0;
      mat[(i0 + 1) * MATW + w] = w1;
      mat[(i0 + 2) * MATW + w] = w2;
      mat[(i0 + 3) * MATW + w] = w3;
    }
    __syncthreads();
    // single-lane bit-walk: next accept == next clear bit (sorted order)
    if (tid == 0) {
      u64 m[MATW];
#pragma unroll
      for (int w = 0; w < MATW; ++w) {
        int base = w * 64;
        m[w] = (base >= K) ? ~0ull
             : ((K - base >= 64) ? 0ull : (~0ull << (K - base)));
      }
      int A = 0;
      while (true) {
        int pos = -1;
#pragma unroll
        for (int w = 0; w < MATW; ++w) {
          if (pos < 0 && m[w] != ~0ull)
            pos = w * 64 + __builtin_ctzll(~m[w]);
        }
        if (pos < 0) break;
        u64 key = keys[pos];
        ss[A] = __uint_as_float(((unsigned int)(key >> 32)) & 0x7FFFFFFFu);
        si[A] = (int)(~((unsigned int)key));
        A++;
        if (A == MAXDET) break;
        const u64* rw = &mat[pos * MATW];
#pragma unroll
        for (int w = 0; w < MATW; ++w) m[w] |= rw[w];
        m[pos >> 6] |= 1ull << (pos & 63);
      }
      need_slow = (A < MAXDET) ? 1 : 0;
    }
    __syncthreads();
    if (!need_slow) return;

    // ---- slow exact path: single-wave sorted scan over full count
    if (tid < 64) {
      const int lane = tid;
      int A = 0;
      bool done = false;
      const int nchunk = (count + 63) >> 6;
      for (int ch = 0; ch < nchunk && !done; ++ch) {
        const int g = (ch << 6) + lane;
        const bool have = g < count;
        u64 key = have ? keys[g] : 0ull;
        const int idx = (int)(~((unsigned int)key));
        const float scv = __uint_as_float(((unsigned int)(key >> 32)) & 0x7FFFFFFFu);
        float4 bx = {0.0f, 0.0f, 0.0f, 0.0f};
        if (have) bx = bxs[idx];
        const float carea = (bx.z - bx.x) * (bx.w - bx.y);
        bool alive = have;
        for (int a = 0; a < A; ++a) {
          float4 abx = accb[a];
          float  aar = acca[a];
          if (alive && iou_gt_pa(abx.x, abx.y, abx.z, abx.w, aar, bx, carea))
            alive = false;
        }
        u64 pend = __ballot(alive);
        while (pend) {
          const int jj = __ffsll((long long)pend) - 1;
          pend &= pend - 1;
          const float jx = __shfl(bx.x, jj);
          const float jy = __shfl(bx.y, jj);
          const float jz = __shfl(bx.z, jj);
          const float jw = __shfl(bx.w, jj);
          if (lane == jj) {
            ss[A] = scv; si[A] = idx;
            accb[A] = bx; acca[A] = carea;
          }
          A++;
          if (A == MAXDET) { done = true; break; }
          if (pend) {
            const float jar = (jz - jx) * (jw - jy);
            bool mine = (pend >> lane) & 1;
            bool sup = mine && iou_gt_pa(jx, jy, jz, jw, jar, bx, carea);
            pend &= ~__ballot(sup);
          }
        }
      }
      if (lane == 0) need_fb = (A < MAXDET) ? 1 : 0;
    }
    __syncthreads();
    if (!need_fb) return;
    fullfb = true;
  }

  // ---- exact full-N fallback (correctness insurance)
  {
    const float* crow = cls + ((size_t)b * N_ANCH) * NCLS + c;  // stride NCLS
    const int base = tid * FB_PER;   // contiguous ownership; 512*96 >= N
    float sc[FB_PER];
#pragma unroll
    for (int m = 0; m < FB_PER; ++m) {
      int n = base + m;
      float v = DEAD;
      if (n < N_ANCH) {
        float r = crow[(size_t)n * NCLS];
        v = (r > SCTHR) ? r : NEGF;
      }
      sc[m] = v;
    }
    __syncthreads();
    for (int k = 0; k < MAXDET; ++k) {
      float bs = DEAD; int bn = 0x7FFFFFFF;
#pragma unroll
      for (int m = 0; m < FB_PER; ++m) {
        if (sc[m] > bs) { bs = sc[m]; bn = base + m; }
      }
      block_argmax(bs, bn, red_s, red_n, &g_s, &g_n);
      const float gs = g_s; const int gn = g_n;
      if (tid == 0) { ss[k] = gs; si[k] = gn; }
      float4 w4 = bxs[gn];
      float ab = (w4.z - w4.x) * (w4.w - w4.y);
#pragma unroll
      for (int m = 0; m < FB_PER; ++m) {
        if (sc[m] > NEGF) {
          float4 e = bxs[base + m];
          if (iou_gt(w4.x, w4.y, w4.z, w4.w, ab, e)) sc[m] = NEGF;
        }
      }
    }
  }
}

// K3: stable global top-300 per batch. Pivot prune (P = min_c key[c][29]
// guarantees >=600 keys >= P >= all top-300), then exact rank-count on ~600.
__global__ __launch_bounds__(512) void topk_kernel(
    const float* __restrict__ sel_s, const int* __restrict__ sel_i,
    const float* __restrict__ boxes, float* __restrict__ out) {
#pragma clang fp contract(off)
  __shared__ u64 keys[NCLS * MAXDET];   // 48 KB
  __shared__ int ccnt[NCLS];
  __shared__ u64 Psh;
  const int b = blockIdx.x;
  const int tid = threadIdx.x;
  const float* ssb = sel_s + (size_t)b * NCLS * MAXDET;
  const int*   sib = sel_i + (size_t)b * NCLS * MAXDET;
  for (int e = tid; e < NCLS * MAXDET; e += 512) {
    unsigned int u = __float_as_uint(ssb[e]);
    u = (u & 0x80000000u) ? ~u : (u | 0x80000000u);    // order-preserving map
    keys[e] = ((u64)u << 32) | (u64)(0xFFFFFFFFu - (unsigned)e);
  }
  __syncthreads();
  if (tid == 0) {
    u64 mn = ~0ull;
    for (int c = 0; c < NCLS; ++c) {
      u64 v = keys[c * MAXDET + 29];
      if (v < mn) mn = v;
    }
    Psh = mn;
  }
  __syncthreads();
  const u64 P = Psh;
  if (tid < NCLS) {                      // per-class count of keys >= P
    const u64* kc = keys + tid * MAXDET;
    int lo = 0, hi = MAXDET;
    while (lo < hi) { int mid = (lo + hi) >> 1; if (kc[mid] >= P) lo = mid + 1; else hi = mid; }
    ccnt[tid] = lo;
  }
  __syncthreads();
  for (int e = tid; e < NCLS * MAXDET; e += 512) {
    int c = e / MAXDET;
    int j = e - c * MAXDET;
    if (j >= ccnt[c]) continue;          // key < P -> rank >= 600 -> excluded
    u64 ke = keys[e];
    int rank = 0;
    for (int c2 = 0; c2 < NCLS; ++c2) {
      const u64* kc = keys + c2 * MAXDET;
      int lo = 0, hi = ccnt[c2];         // keys beyond ccnt are < P <= ke
      while (lo < hi) {
        int mid = (lo + hi) >> 1;
        if (kc[mid] > ke) lo = mid + 1; else hi = mid;
      }
      rank += lo;
    }
    if (rank < MAXDET) {
      float s = ssb[e];
      int   n = sib[e];
      int   cc = c;
      bool valid = (s > NEGF * 0.5f);
      float4 bx = ((const float4*)boxes)[(size_t)b * N_ANCH + n];
      float* ob = out + ((size_t)b * MAXDET + rank) * 4;
      ob[0] = valid ? bx.x : -1.0f;
      ob[1] = valid ? bx.y : -1.0f;
      ob[2] = valid ? bx.z : -1.0f;
      ob[3] = valid ? bx.w : -1.0f;
      out[(size_t)BATCH * MAXDET * 4 + (size_t)b * MAXDET + rank] = valid ? s : -1.0f;
      out[(size_t)BATCH * MAXDET * 5 + (size_t)b * MAXDET + rank] =
          valid ? (float)cc : -1.0f;
    }
  }
}

extern "C" void kernel_launch(void* const* d_in, const int* in_sizes, int n_in,
                              void* d_out, int out_size, void* d_ws, size_t ws_size,
                              hipStream_t stream) {
  (void)in_sizes; (void)n_in; (void)out_size; (void)ws_size;
  const float* anchors = (const float*)d_in[1];
  const float* deltas  = (const float*)d_in[2];
  const float* cls     = (const float*)d_in[3];   // d_in[0] = image: only shape used
  char* ws = (char*)d_ws;
  float* boxes  = (float*)(ws + OFF_BOXES);
  float* cand_s = (float*)(ws + OFF_CS);
  int*   cand_i = (int*)  (ws + OFF_CI);
  int*   cnt    = (int*)  (ws + OFF_CNT);
  float* sel_s  = (float*)(ws + OFF_SS);
  int*   sel_i  = (int*)  (ws + OFF_SI);

  hipMemsetAsync(cnt, 0, SZ_CNT, stream);   // ws is re-poisoned 0xAA each call

  dec_gather<<<(BATCH * N_ANCH + 255) / 256, 256, 0, stream>>>(
      anchors, deltas, cls, boxes, cand_s, cand_i, cnt);
  nms_kernel<<<BATCH * NCLS, NMS_T, 0, stream>>>(
      cls, boxes, cand_s, cand_i, cnt, sel_s, sel_i);
  topk_kernel<<<BATCH, 512, 0, stream>>>(sel_s, sel_i, boxes, (float*)d_out);
}